// Round 13
// baseline (1052.302 us; speedup 1.0000x reference)
//
#include <hip/hip_runtime.h>
#include <hip/hip_bf16.h>

#define Df 384
#define Hf 768
#define SCAN_CH 4096

typedef __bf16 bf16x8 __attribute__((ext_vector_type(8)));
typedef float f32x4 __attribute__((ext_vector_type(4)));

struct __attribute__((aligned(4))) U12 { unsigned int x, y, z; };

__device__ inline unsigned short f2bf(float f) {
    __hip_bfloat16 h = __float2bfloat16(f);
    return __builtin_bit_cast(unsigned short, h);
}
__device__ inline float bf2f(unsigned short u) {
    unsigned int v = ((unsigned int)u) << 16;
    return __builtin_bit_cast(float, v);
}
__device__ inline float lobf(unsigned int v) { return bf2f((unsigned short)(v & 0xffff)); }
__device__ inline float hibf(unsigned int v) { return bf2f((unsigned short)(v >> 16)); }
__device__ inline unsigned int pk2(float a, float b) {
    return (unsigned int)f2bf(a) | ((unsigned int)f2bf(b) << 16);
}
__device__ inline float gelu_(float v) {
    return 0.5f * v * (1.0f + erff(v * 0.70710678118654752f));
}
// direct global->LDS, 16B/lane; LDS dest is WAVE-UNIFORM base, HW adds lane*16.
__device__ inline void gload16(const void* g, void* l) {
    __builtin_amdgcn_global_load_lds(
        (const __attribute__((address_space(1))) unsigned int*)g,
        (__attribute__((address_space(3))) unsigned int*)l, 16, 0, 0);
}

// ---- BN column statistics ----
__global__ void bn_stats(const float* __restrict__ x, float* __restrict__ stats, int N) {
    int t = threadIdx.x;                 // 192 threads
    int c4 = (t % 96) * 4;
    int rs = t / 96;
    float s0 = 0, s1 = 0, s2 = 0, s3 = 0, q0 = 0, q1 = 0, q2 = 0, q3 = 0;
    for (int r = blockIdx.x * 2 + rs; r < N; r += gridDim.x * 2) {
        float4 v = *(const float4*)(x + (size_t)r * Df + c4);
        s0 += v.x; s1 += v.y; s2 += v.z; s3 += v.w;
        q0 += v.x * v.x; q1 += v.y * v.y; q2 += v.z * v.z; q3 += v.w * v.w;
    }
    unsafeAtomicAdd(&stats[c4 + 0], s0);
    unsafeAtomicAdd(&stats[c4 + 1], s1);
    unsafeAtomicAdd(&stats[c4 + 2], s2);
    unsafeAtomicAdd(&stats[c4 + 3], s3);
    unsafeAtomicAdd(&stats[Df + c4 + 0], q0);
    unsafeAtomicAdd(&stats[Df + c4 + 1], q1);
    unsafeAtomicAdd(&stats[Df + c4 + 2], q2);
    unsafeAtomicAdd(&stats[Df + c4 + 3], q3);
}

__global__ void bn_finalize(const float* __restrict__ stats,
                            const float* __restrict__ gamma,
                            const float* __restrict__ beta,
                            float* __restrict__ coef, int N) {
    int c = threadIdx.x; // 384
    float invN = 1.0f / (float)N;
    float mu = stats[c] * invN;
    float var = stats[Df + c] * invN - mu * mu;
    float rs = rsqrtf(var + 1e-5f);
    float a = gamma[c] * rs;
    coef[c] = a;
    coef[Df + c] = beta[c] - mu * a;
}

// ---- h = x*a + b  ->  bf16 ----
__global__ void h_kernel(const float* __restrict__ x, const float* __restrict__ coef,
                         unsigned short* __restrict__ hb, int tot8) {
    int i = blockIdx.x * 256 + threadIdx.x;
    if (i >= tot8) return;
    size_t base = (size_t)i * 8;
    int c = (int)(base % Df);
    float4 x0 = *(const float4*)(x + base);
    float4 x1 = *(const float4*)(x + base + 4);
    const float* a = coef + c;
    const float* b = coef + Df + c;
    uint4 o;
    o.x = pk2(x0.x * a[0] + b[0], x0.y * a[1] + b[1]);
    o.y = pk2(x0.z * a[2] + b[2], x0.w * a[3] + b[3]);
    o.z = pk2(x1.x * a[4] + b[4], x1.y * a[5] + b[5]);
    o.w = pk2(x1.z * a[6] + b[6], x1.w * a[7] + b[7]);
    *(uint4*)(hb + base) = o;
}

// ---- all three weight transposes in one dispatch ----
__global__ void wtrans3(const float* __restrict__ We, const float* __restrict__ W1,
                        const float* __restrict__ W2,
                        unsigned short* __restrict__ WeT, unsigned short* __restrict__ W1T,
                        unsigned short* __restrict__ W2T) {
    int idx = blockIdx.x * 256 + threadIdx.x;
    if (idx < Df * Df) {
        int k = idx / Df, n = idx % Df;
        WeT[n * Df + k] = f2bf(We[idx]);
    } else if (idx < Df * Df + Df * Hf) {
        int i = idx - Df * Df;
        int k = i / Hf, n = i % Hf;
        W1T[(size_t)n * Df + k] = f2bf(W1[i]);
    } else if (idx < Df * Df + 2 * Df * Hf) {
        int i = idx - (Df * Df + Df * Hf);
        int k = i / Df, n = i % Df;
        W2T[(size_t)n * Hf + k] = f2bf(W2[i]);
    }
}

// ---- CSR build ----
__global__ void degree_k(const int* __restrict__ dst, int* __restrict__ deg, int E) {
    int e = blockIdx.x * 256 + threadIdx.x;
    if (e < E) atomicAdd(&deg[dst[e]], 1);
}

__global__ void scan1(const int* __restrict__ deg, int* __restrict__ off,
                      int* __restrict__ sums, int N) {
    __shared__ int ts[256];
    int t = threadIdx.x;
    int base = blockIdx.x * SCAN_CH + t * 16;
    int v[16];
    int s = 0;
    for (int j = 0; j < 16; j++) {
        int idx = base + j;
        int d = (idx < N) ? deg[idx] : 0;
        v[j] = s;
        s += d;
    }
    ts[t] = s;
    __syncthreads();
    for (int o = 1; o < 256; o <<= 1) {
        int add = (t >= o) ? ts[t - o] : 0;
        __syncthreads();
        ts[t] += add;
        __syncthreads();
    }
    int pre = t ? ts[t - 1] : 0;
    for (int j = 0; j < 16; j++) {
        int idx = base + j;
        if (idx < N) off[idx] = pre + v[j];
    }
    if (t == 255) sums[blockIdx.x] = ts[255];
}

__global__ void scan2(int* __restrict__ sums, int nb) {
    int acc = 0;
    for (int b = 0; b < nb; b++) { int v = sums[b]; sums[b] = acc; acc += v; }
    sums[nb] = acc;
}

__global__ void scan3(int* __restrict__ off, const int* __restrict__ sums, int N, int nb) {
    int idx = blockIdx.x * 256 + threadIdx.x;
    if (idx < N) off[idx] += sums[idx / SCAN_CH];
    else if (idx == N) off[N] = sums[nb];
}

// fill: pose[e] = CSR slot of edge e; srcp[slot] = src node of that edge
__global__ void fill_k(const int* __restrict__ dst, const int* __restrict__ src,
                       int* __restrict__ cursor, int* __restrict__ srcp,
                       int* __restrict__ pose, int E) {
    int e = blockIdx.x * 256 + threadIdx.x;
    if (e >= E) return;
    int pos = atomicAdd(&cursor[dst[e]], 1);
    srcp[pos] = src[e];
    pose[e] = pos;
}

// ---- gather-reduce: z[i] = (1+eps)*h[i] + sum relu(msgl[p] + h[srcp[p]]) ----
__global__ __launch_bounds__(256) void aggregate(
    const unsigned short* __restrict__ msgl, const unsigned short* __restrict__ hb,
    const int* __restrict__ off, const int* __restrict__ srcp,
    const float* __restrict__ epsp,
    unsigned short* __restrict__ zb, int N) {
    int lane = threadIdx.x & 63;
    int wid = threadIdx.x >> 6;
    int nwaves = gridDim.x * 4;
    float s1p = 1.0f + epsp[0];
    int loff = lane * 6;
    for (int i = blockIdx.x * 4 + wid; i < N; i += nwaves) {
        int o0 = off[i], o1 = off[i + 1];
        float a0 = 0, a1 = 0, a2 = 0, a3 = 0, a4 = 0, a5 = 0;
        for (int p = o0; p < o1; ++p) {
            int s = srcp[p];
            U12 mv = *(const U12*)(msgl + (size_t)p * Df + loff);
            U12 hv = *(const U12*)(hb + (size_t)s * Df + loff);
            a0 += fmaxf(lobf(mv.x) + lobf(hv.x), 0.f);
            a1 += fmaxf(hibf(mv.x) + hibf(hv.x), 0.f);
            a2 += fmaxf(lobf(mv.y) + lobf(hv.y), 0.f);
            a3 += fmaxf(hibf(mv.y) + hibf(hv.y), 0.f);
            a4 += fmaxf(lobf(mv.z) + lobf(hv.z), 0.f);
            a5 += fmaxf(hibf(mv.z) + hibf(hv.z), 0.f);
        }
        U12 hv = *(const U12*)(hb + (size_t)i * Df + loff);
        U12 o;
        o.x = pk2(s1p * lobf(hv.x) + a0, s1p * hibf(hv.x) + a1);
        o.y = pk2(s1p * lobf(hv.y) + a2, s1p * hibf(hv.y) + a3);
        o.z = pk2(s1p * lobf(hv.z) + a4, s1p * hibf(hv.z) + a5);
        *(U12*)(zb + (size_t)i * Df + loff) = o;
    }
}

// ---- Strip GEMM: one block = one 128-row strip x one 64-col slice ----
// Grid col-fastest + m204 XCD chunking -> same-strip slices co-resident on one
// XCD's L2. B-slice staged once per 384-k half (48KB, L2-resident weights ->
// free); K-loop BARRIER-FREE; A streams global->regs with next-tile prefetch.
// ABF16=false: A is f32, packed to bf16 in registers (v_cvt_pk_bf16_f32).
// EPI 1: bf16 gelu out via LDS-staged full-line stores.
// EPI 2: f32 out = xres + gelu(acc+bias), direct coalesced stores.
// EPI 3: bf16 out rows permuted by pose, LDS-staged full-line stores.
template <int KTOT, int EPI, bool ABF16>
__global__ __launch_bounds__(256, 3) void gemm_strip(
    const void* __restrict__ Ap, const unsigned short* __restrict__ Bt,
    const float* __restrict__ bias, const int* __restrict__ pose,
    unsigned short* __restrict__ outb, const float* __restrict__ xres,
    float* __restrict__ outf, int M, int ncols, int ldo) {
    constexpr int NKT = KTOT / 32;    // total k-tiles
    constexpr int NH = KTOT / 384;    // 48KB B halves (1 or 2)
    __shared__ __align__(16) unsigned short Bs[64 * 48 * 8];   // 48 KB

    const int t = threadIdx.x;
    const int nwg = gridDim.x;
    const int orig = blockIdx.x;
    const int xcd = orig & 7;
    const int q = nwg >> 3, r = nwg & 7;
    const int wgid = (xcd < r ? xcd * (q + 1) : r * (q + 1) + (xcd - r) * q) + (orig >> 3);
    const int strip = wgid / ncols;
    const int cb = (wgid - strip * ncols) * 64;

    const int lane = t & 63;
    const int wid = t >> 6;
    const int fr = lane & 15;
    const int kg = lane >> 4;

    auto stageB = [&](int koff) {
#pragma unroll
        for (int s_ = 0; s_ < 12; s_++) {
            int u = s_ * 256 + t;
            int col = u / 48;
            int pos = u - col * 48;
            gload16(Bt + (size_t)(cb + col) * KTOT + koff + ((pos ^ (col & 7)) << 3),
                    &Bs[(s_ * 256 + wid * 64) * 8]);
        }
    };

    int ra0 = strip * 128 + wid * 32 + fr;      if (ra0 >= M) ra0 = M - 1;
    int ra1 = strip * 128 + wid * 32 + 16 + fr; if (ra1 >= M) ra1 = M - 1;
    const unsigned short* pA0b; const unsigned short* pA1b;
    const float* pA0f; const float* pA1f;
    if constexpr (ABF16) {
        pA0b = (const unsigned short*)Ap + (size_t)ra0 * KTOT + kg * 8;
        pA1b = (const unsigned short*)Ap + (size_t)ra1 * KTOT + kg * 8;
    } else {
        pA0f = (const float*)Ap + (size_t)ra0 * KTOT + kg * 8;
        pA1f = (const float*)Ap + (size_t)ra1 * KTOT + kg * 8;
    }

    f32x4 acc[2][4];
#pragma unroll
    for (int i = 0; i < 2; i++)
#pragma unroll
        for (int j = 0; j < 4; j++) acc[i][j] = (f32x4){0.f, 0.f, 0.f, 0.f};

    stageB(0);
    uint4 a00, a01, a10, a11;
    if constexpr (ABF16) {
        a00 = *(const uint4*)(pA0b);
        a10 = *(const uint4*)(pA1b);
    } else {
        a00 = *(const uint4*)(pA0f);     a01 = *(const uint4*)(pA0f + 4);
        a10 = *(const uint4*)(pA1f);     a11 = *(const uint4*)(pA1f + 4);
    }
    asm volatile("s_waitcnt vmcnt(0)" ::: "memory");
    __builtin_amdgcn_s_barrier();

#pragma unroll
    for (int h = 0; h < NH; h++) {
        if (h > 0) {
            __syncthreads();          // all waves done with previous B half
            stageB(h * 384);
            asm volatile("s_waitcnt vmcnt(0)" ::: "memory");
            __builtin_amdgcn_s_barrier();
        }
#pragma unroll
        for (int ktl = 0; ktl < 12; ktl++) {
            const int kt = h * 12 + ktl;
            uint4 n00, n01, n10, n11;
            if (kt < NKT - 1) {
                if constexpr (ABF16) {
                    n00 = *(const uint4*)(pA0b + (kt + 1) * 32);
                    n10 = *(const uint4*)(pA1b + (kt + 1) * 32);
                } else {
                    n00 = *(const uint4*)(pA0f + (kt + 1) * 32);
                    n01 = *(const uint4*)(pA0f + (kt + 1) * 32 + 4);
                    n10 = *(const uint4*)(pA1f + (kt + 1) * 32);
                    n11 = *(const uint4*)(pA1f + (kt + 1) * 32 + 4);
                }
            } else { n00 = a00; n01 = a01; n10 = a10; n11 = a11; }
            bf16x8 bf[4];
#pragma unroll
            for (int j = 0; j < 4; j++) {
                const int cl = j * 16 + fr;
                const int unit = (ktl * 4 + kg) ^ (cl & 7);
                bf[j] = *(const bf16x8*)&Bs[(cl * 48 + unit) * 8];
            }
            bf16x8 av0, av1;
            if constexpr (ABF16) {
                av0 = __builtin_bit_cast(bf16x8, a00);
                av1 = __builtin_bit_cast(bf16x8, a10);
            } else {
                float4 x0 = __builtin_bit_cast(float4, a00);
                float4 x1 = __builtin_bit_cast(float4, a01);
                uint4 u;
                u.x = pk2(x0.x, x0.y); u.y = pk2(x0.z, x0.w);
                u.z = pk2(x1.x, x1.y); u.w = pk2(x1.z, x1.w);
                av0 = __builtin_bit_cast(bf16x8, u);
                float4 y0 = __builtin_bit_cast(float4, a10);
                float4 y1 = __builtin_bit_cast(float4, a11);
                uint4 v;
                v.x = pk2(y0.x, y0.y); v.y = pk2(y0.z, y0.w);
                v.z = pk2(y1.x, y1.y); v.w = pk2(y1.z, y1.w);
                av1 = __builtin_bit_cast(bf16x8, v);
            }
#pragma unroll
            for (int j = 0; j < 4; j++) {
                acc[0][j] = __builtin_amdgcn_mfma_f32_16x16x32_bf16(av0, bf[j], acc[0][j], 0, 0, 0);
                acc[1][j] = __builtin_amdgcn_mfma_f32_16x16x32_bf16(av1, bf[j], acc[1][j], 0, 0, 0);
            }
            a00 = n00; a01 = n01; a10 = n10; a11 = n11;
        }
    }

    float bv[4];
#pragma unroll
    for (int j = 0; j < 4; j++) bv[j] = bias[cb + j * 16 + fr];
    const int kg4 = kg * 4;
    const int rbase = strip * 128;

    if (EPI == 2) {
#pragma unroll
        for (int i = 0; i < 2; i++) {
            const int rb = rbase + wid * 32 + i * 16 + kg4;
#pragma unroll
            for (int rr = 0; rr < 4; rr++) {
                const int row = rb + rr;
                if (row < M) {
#pragma unroll
                    for (int j = 0; j < 4; j++) {
                        size_t o = (size_t)row * ldo + cb + j * 16 + fr;
                        outf[o] = xres[o] + gelu_(acc[i][j][rr] + bv[j]);
                    }
                }
            }
        }
    } else {
        // stage C through dead B-LDS (stride 72 shorts: 16B-aligned rows)
        __syncthreads();
        unsigned short* Ct = Bs;
#pragma unroll
        for (int i = 0; i < 2; i++) {
            const int rl = wid * 32 + i * 16 + kg4;
#pragma unroll
            for (int j = 0; j < 4; j++) {
#pragma unroll
                for (int rr = 0; rr < 4; rr++) {
                    float v = acc[i][j][rr] + bv[j];
                    Ct[(rl + rr) * 72 + j * 16 + fr] = f2bf(EPI == 1 ? gelu_(v) : v);
                }
            }
        }
        __syncthreads();
#pragma unroll
        for (int s_ = 0; s_ < 4; s_++) {
            int u = s_ * 256 + t;
            int rl = u >> 3, seg = u & 7;
            int grow = rbase + rl;
            if (grow < M) {
                size_t drow = (EPI == 3) ? (size_t)pose[grow] : (size_t)grow;
                *(uint4*)(outb + drow * ldo + cb + seg * 8) =
                    *(const uint4*)&Ct[rl * 72 + seg * 8];
            }
        }
    }
}

extern "C" void kernel_launch(void* const* d_in, const int* in_sizes, int n_in,
                              void* d_out, int out_size, void* d_ws, size_t ws_size,
                              hipStream_t stream) {
    const float* x = (const float*)d_in[0];
    const float* ea = (const float*)d_in[1];
    const float* gamma = (const float*)d_in[2];
    const float* beta = (const float*)d_in[3];
    const float* epsp = (const float*)d_in[4];
    const float* W_edge = (const float*)d_in[5];
    const float* b_edge = (const float*)d_in[6];
    const float* W1 = (const float*)d_in[7];
    const float* b1 = (const float*)d_in[8];
    const float* W2 = (const float*)d_in[9];
    const float* b2 = (const float*)d_in[10];
    const int* eidx = (const int*)d_in[11];
    float* out = (float*)d_out;
    const int N = in_sizes[0] / Df;
    const int E = in_sizes[1] / Df;
    const int* esrc = eidx;
    const int* edst = eidx + E;

    char* w = (char*)d_ws;
    size_t off_ = 0;
    auto alloc = [&](size_t bytes) { char* p = w + off_; off_ += (bytes + 255) & ~(size_t)255; return p; };
    float* stats = (float*)alloc(2 * Df * sizeof(float));
    float* coef = (float*)alloc(2 * Df * sizeof(float));
    unsigned short* hb = (unsigned short*)alloc((size_t)N * Df * 2);
    unsigned short* zb = (unsigned short*)alloc((size_t)N * Df * 2);
    unsigned short* tb = (unsigned short*)alloc((size_t)N * Hf * 2);
    unsigned short* WeT = (unsigned short*)alloc((size_t)Df * Df * 2);
    unsigned short* W1T = (unsigned short*)alloc((size_t)Df * Hf * 2);
    unsigned short* W2T = (unsigned short*)alloc((size_t)Hf * Df * 2);
    int* deg = (int*)alloc((size_t)(N + 1) * 4);      // reused as fill cursor
    int* offs = (int*)alloc((size_t)(N + 1) * 4);
    int* srcp = (int*)alloc((size_t)E * 4);
    int* pose = (int*)alloc((size_t)E * 4);
    int* sums = (int*)alloc(64 * 4);
    size_t msgl_bytes = (size_t)E * Df * 2;
    unsigned short* msgl;
    if (off_ + msgl_bytes <= ws_size) msgl = (unsigned short*)alloc(msgl_bytes);
    else msgl = (unsigned short*)d_out;   // dead until final GEMM writes it
    (void)n_in; (void)out_size;

    hipMemsetAsync(stats, 0, 2 * Df * sizeof(float), stream);
    hipMemsetAsync(deg, 0, (size_t)N * 4, stream);

    // BN + h
    bn_stats<<<1024, 192, 0, stream>>>(x, stats, N);
    bn_finalize<<<1, Df, 0, stream>>>(stats, gamma, beta, coef, N);
    int tot8 = N * Df / 8;
    h_kernel<<<(tot8 + 255) / 256, 256, 0, stream>>>(x, coef, hb, tot8);

    // weights (one dispatch)
    wtrans3<<<(Df * Df + 2 * Df * Hf + 255) / 256, 256, 0, stream>>>(
        W_edge, W1, W2, WeT, W1T, W2T);

    // CSR by dst
    int nb = (N + SCAN_CH - 1) / SCAN_CH;
    degree_k<<<(E + 255) / 256, 256, 0, stream>>>(edst, deg, E);
    scan1<<<nb, 256, 0, stream>>>(deg, offs, sums, N);
    scan2<<<1, 1, 0, stream>>>(sums, nb);
    scan3<<<(N + 256) / 256, 256, 0, stream>>>(offs, sums, N, nb);
    hipMemcpyAsync(deg, offs, (size_t)N * 4, hipMemcpyDeviceToDevice, stream);
    fill_k<<<(E + 255) / 256, 256, 0, stream>>>(edst, esrc, deg, srcp, pose, E);

    // edge linear (strip, f32 A): msgl[pose[e]] = ea[e] @ We^T + b_edge
    int estrips = (E + 127) / 128;
    gemm_strip<Df, 3, false><<<dim3(estrips * (Df / 64)), 256, 0, stream>>>(
        ea, WeT, b_edge, pose, msgl, nullptr, nullptr, E, Df / 64, Df);

    // gather-reduce -> z (bf16)
    aggregate<<<2048, 256, 0, stream>>>(msgl, hb, offs, srcp, epsp, zb, N);

    // GEMM1 (strip): tb = bf16(gelu(zb @ W1T^T + b1))
    int strips = (N + 127) / 128;
    gemm_strip<Df, 1, true><<<dim3(strips * (Hf / 64)), 256, 0, stream>>>(
        zb, W1T, b1, nullptr, tb, nullptr, nullptr, N, Hf / 64, Hf);

    // GEMM2 (strip, K=768 two halves): out = x + gelu(tb @ W2T^T + b2)
    gemm_strip<Hf, 2, true><<<dim3(strips * (Df / 64)), 256, 0, stream>>>(
        tb, W2T, b2, nullptr, nullptr, x, out, N, Df / 64, Df);
}

// Round 14
// 1029.217 us; speedup vs baseline: 1.0224x; 1.0224x over previous
//
#include <hip/hip_runtime.h>
#include <hip/hip_bf16.h>

#define Df 384
#define Hf 768
#define SCAN_CH 4096

typedef __bf16 bf16x8 __attribute__((ext_vector_type(8)));
typedef float f32x4 __attribute__((ext_vector_type(4)));

struct __attribute__((aligned(4))) U12 { unsigned int x, y, z; };

__device__ inline unsigned short f2bf(float f) {
    __hip_bfloat16 h = __float2bfloat16(f);
    return __builtin_bit_cast(unsigned short, h);
}
__device__ inline float bf2f(unsigned short u) {
    unsigned int v = ((unsigned int)u) << 16;
    return __builtin_bit_cast(float, v);
}
__device__ inline float lobf(unsigned int v) { return bf2f((unsigned short)(v & 0xffff)); }
__device__ inline float hibf(unsigned int v) { return bf2f((unsigned short)(v >> 16)); }
__device__ inline unsigned int pk2(float a, float b) {
    return (unsigned int)f2bf(a) | ((unsigned int)f2bf(b) << 16);
}
__device__ inline float gelu_(float v) {
    return 0.5f * v * (1.0f + erff(v * 0.70710678118654752f));
}
// direct global->LDS, 16B/lane; LDS dest is WAVE-UNIFORM base, HW adds lane*16.
__device__ inline void gload16(const void* g, void* l) {
    __builtin_amdgcn_global_load_lds(
        (const __attribute__((address_space(1))) unsigned int*)g,
        (__attribute__((address_space(3))) unsigned int*)l, 16, 0, 0);
}

// ---- BN column statistics ----
__global__ void bn_stats(const float* __restrict__ x, float* __restrict__ stats, int N) {
    int t = threadIdx.x;                 // 192 threads
    int c4 = (t % 96) * 4;
    int rs = t / 96;
    float s0 = 0, s1 = 0, s2 = 0, s3 = 0, q0 = 0, q1 = 0, q2 = 0, q3 = 0;
    for (int r = blockIdx.x * 2 + rs; r < N; r += gridDim.x * 2) {
        float4 v = *(const float4*)(x + (size_t)r * Df + c4);
        s0 += v.x; s1 += v.y; s2 += v.z; s3 += v.w;
        q0 += v.x * v.x; q1 += v.y * v.y; q2 += v.z * v.z; q3 += v.w * v.w;
    }
    unsafeAtomicAdd(&stats[c4 + 0], s0);
    unsafeAtomicAdd(&stats[c4 + 1], s1);
    unsafeAtomicAdd(&stats[c4 + 2], s2);
    unsafeAtomicAdd(&stats[c4 + 3], s3);
    unsafeAtomicAdd(&stats[Df + c4 + 0], q0);
    unsafeAtomicAdd(&stats[Df + c4 + 1], q1);
    unsafeAtomicAdd(&stats[Df + c4 + 2], q2);
    unsafeAtomicAdd(&stats[Df + c4 + 3], q3);
}

__global__ void bn_finalize(const float* __restrict__ stats,
                            const float* __restrict__ gamma,
                            const float* __restrict__ beta,
                            float* __restrict__ coef, int N) {
    int c = threadIdx.x; // 384
    float invN = 1.0f / (float)N;
    float mu = stats[c] * invN;
    float var = stats[Df + c] * invN - mu * mu;
    float rs = rsqrtf(var + 1e-5f);
    float a = gamma[c] * rs;
    coef[c] = a;
    coef[Df + c] = beta[c] - mu * a;
}

// ---- h = x*a + b  ->  bf16 ----
__global__ void h_kernel(const float* __restrict__ x, const float* __restrict__ coef,
                         unsigned short* __restrict__ hb, int tot8) {
    int i = blockIdx.x * 256 + threadIdx.x;
    if (i >= tot8) return;
    size_t base = (size_t)i * 8;
    int c = (int)(base % Df);
    float4 x0 = *(const float4*)(x + base);
    float4 x1 = *(const float4*)(x + base + 4);
    const float* a = coef + c;
    const float* b = coef + Df + c;
    uint4 o;
    o.x = pk2(x0.x * a[0] + b[0], x0.y * a[1] + b[1]);
    o.y = pk2(x0.z * a[2] + b[2], x0.w * a[3] + b[3]);
    o.z = pk2(x1.x * a[4] + b[4], x1.y * a[5] + b[5]);
    o.w = pk2(x1.z * a[6] + b[6], x1.w * a[7] + b[7]);
    *(uint4*)(hb + base) = o;
}

// ---- all three weight transposes in one dispatch ----
__global__ void wtrans3(const float* __restrict__ We, const float* __restrict__ W1,
                        const float* __restrict__ W2,
                        unsigned short* __restrict__ WeT, unsigned short* __restrict__ W1T,
                        unsigned short* __restrict__ W2T) {
    int idx = blockIdx.x * 256 + threadIdx.x;
    if (idx < Df * Df) {
        int k = idx / Df, n = idx % Df;
        WeT[n * Df + k] = f2bf(We[idx]);
    } else if (idx < Df * Df + Df * Hf) {
        int i = idx - Df * Df;
        int k = i / Hf, n = i % Hf;
        W1T[(size_t)n * Df + k] = f2bf(W1[i]);
    } else if (idx < Df * Df + 2 * Df * Hf) {
        int i = idx - (Df * Df + Df * Hf);
        int k = i / Df, n = i % Df;
        W2T[(size_t)n * Hf + k] = f2bf(W2[i]);
    }
}

// ---- CSR build ----
__global__ void degree_k(const int* __restrict__ dst, int* __restrict__ deg, int E) {
    int e = blockIdx.x * 256 + threadIdx.x;
    if (e < E) atomicAdd(&deg[dst[e]], 1);
}

__global__ void scan1(const int* __restrict__ deg, int* __restrict__ off,
                      int* __restrict__ sums, int N) {
    __shared__ int ts[256];
    int t = threadIdx.x;
    int base = blockIdx.x * SCAN_CH + t * 16;
    int v[16];
    int s = 0;
    for (int j = 0; j < 16; j++) {
        int idx = base + j;
        int d = (idx < N) ? deg[idx] : 0;
        v[j] = s;
        s += d;
    }
    ts[t] = s;
    __syncthreads();
    for (int o = 1; o < 256; o <<= 1) {
        int add = (t >= o) ? ts[t - o] : 0;
        __syncthreads();
        ts[t] += add;
        __syncthreads();
    }
    int pre = t ? ts[t - 1] : 0;
    for (int j = 0; j < 16; j++) {
        int idx = base + j;
        if (idx < N) off[idx] = pre + v[j];
    }
    if (t == 255) sums[blockIdx.x] = ts[255];
}

__global__ void scan2(int* __restrict__ sums, int nb) {
    int acc = 0;
    for (int b = 0; b < nb; b++) { int v = sums[b]; sums[b] = acc; acc += v; }
    sums[nb] = acc;
}

__global__ void scan3(int* __restrict__ off, const int* __restrict__ sums, int N, int nb) {
    int idx = blockIdx.x * 256 + threadIdx.x;
    if (idx < N) off[idx] += sums[idx / SCAN_CH];
    else if (idx == N) off[N] = sums[nb];
}

// fill: pose[e] = CSR slot of edge e; srcp[slot] = src node of that edge
__global__ void fill_k(const int* __restrict__ dst, const int* __restrict__ src,
                       int* __restrict__ cursor, int* __restrict__ srcp,
                       int* __restrict__ pose, int E) {
    int e = blockIdx.x * 256 + threadIdx.x;
    if (e >= E) return;
    int pos = atomicAdd(&cursor[dst[e]], 1);
    srcp[pos] = src[e];
    pose[e] = pos;
}

// ---- gather-reduce: z[i] = (1+eps)*h[i] + sum relu(msgl[p] + h[srcp[p]]) ----
__global__ __launch_bounds__(256) void aggregate(
    const unsigned short* __restrict__ msgl, const unsigned short* __restrict__ hb,
    const int* __restrict__ off, const int* __restrict__ srcp,
    const float* __restrict__ epsp,
    unsigned short* __restrict__ zb, int N) {
    int lane = threadIdx.x & 63;
    int wid = threadIdx.x >> 6;
    int nwaves = gridDim.x * 4;
    float s1p = 1.0f + epsp[0];
    int loff = lane * 6;
    for (int i = blockIdx.x * 4 + wid; i < N; i += nwaves) {
        int o0 = off[i], o1 = off[i + 1];
        float a0 = 0, a1 = 0, a2 = 0, a3 = 0, a4 = 0, a5 = 0;
        for (int p = o0; p < o1; ++p) {
            int s = srcp[p];
            U12 mv = *(const U12*)(msgl + (size_t)p * Df + loff);
            U12 hv = *(const U12*)(hb + (size_t)s * Df + loff);
            a0 += fmaxf(lobf(mv.x) + lobf(hv.x), 0.f);
            a1 += fmaxf(hibf(mv.x) + hibf(hv.x), 0.f);
            a2 += fmaxf(lobf(mv.y) + lobf(hv.y), 0.f);
            a3 += fmaxf(hibf(mv.y) + hibf(hv.y), 0.f);
            a4 += fmaxf(lobf(mv.z) + lobf(hv.z), 0.f);
            a5 += fmaxf(hibf(mv.z) + hibf(hv.z), 0.f);
        }
        U12 hv = *(const U12*)(hb + (size_t)i * Df + loff);
        U12 o;
        o.x = pk2(s1p * lobf(hv.x) + a0, s1p * hibf(hv.x) + a1);
        o.y = pk2(s1p * lobf(hv.y) + a2, s1p * hibf(hv.y) + a3);
        o.z = pk2(s1p * lobf(hv.z) + a4, s1p * hibf(hv.z) + a5);
        *(U12*)(zb + (size_t)i * Df + loff) = o;
    }
}

// ---- Strip GEMM (depth-3 A prefetch): one block = 128-row strip x 64-col slice ----
// B-slice in LDS once per 384-k half (48KB); K-loop barrier-free; A streams
// global->regs with THREE tiles in flight (covers HBM-miss latency at
// 3 waves/SIMD). EPI 1: bf16 gelu out via LDS-staged full-line stores.
// EPI 2: f32 out = xres + gelu(acc+bias), direct coalesced stores.
template <int KTOT, int EPI>
__global__ __launch_bounds__(256, 3) void gemm_strip(
    const unsigned short* __restrict__ Ab, const unsigned short* __restrict__ Bt,
    const float* __restrict__ bias,
    unsigned short* __restrict__ outb, const float* __restrict__ xres,
    float* __restrict__ outf, int M, int ncols, int ldo) {
    constexpr int NKT = KTOT / 32;    // total k-tiles (12 or 24)
    constexpr int NH = KTOT / 384;    // 48KB B halves (1 or 2)
    __shared__ __align__(16) unsigned short Bs[64 * 48 * 8];   // 48 KB

    const int t = threadIdx.x;
    const int nwg = gridDim.x;
    const int orig = blockIdx.x;
    const int xcd = orig & 7;
    const int q = nwg >> 3, r = nwg & 7;
    const int wgid = (xcd < r ? xcd * (q + 1) : r * (q + 1) + (xcd - r) * q) + (orig >> 3);
    const int strip = wgid / ncols;
    const int cb = (wgid - strip * ncols) * 64;

    const int lane = t & 63;
    const int wid = t >> 6;
    const int fr = lane & 15;
    const int kg = lane >> 4;

    auto stageB = [&](int koff) {
#pragma unroll
        for (int s_ = 0; s_ < 12; s_++) {
            int u = s_ * 256 + t;
            int col = u / 48;
            int pos = u - col * 48;
            gload16(Bt + (size_t)(cb + col) * KTOT + koff + ((pos ^ (col & 7)) << 3),
                    &Bs[(s_ * 256 + wid * 64) * 8]);
        }
    };

    int ra0 = strip * 128 + wid * 32 + fr;      if (ra0 >= M) ra0 = M - 1;
    int ra1 = strip * 128 + wid * 32 + 16 + fr; if (ra1 >= M) ra1 = M - 1;
    const unsigned short* pA0 = Ab + (size_t)ra0 * KTOT + kg * 8;
    const unsigned short* pA1 = Ab + (size_t)ra1 * KTOT + kg * 8;

    f32x4 acc[2][4];
#pragma unroll
    for (int i = 0; i < 2; i++)
#pragma unroll
        for (int j = 0; j < 4; j++) acc[i][j] = (f32x4){0.f, 0.f, 0.f, 0.f};

    stageB(0);
    // depth-3 A prefetch: named slots, statically rotated
    uint4 p0a = *(const uint4*)(pA0);       uint4 p0b = *(const uint4*)(pA1);
    uint4 p1a = *(const uint4*)(pA0 + 32);  uint4 p1b = *(const uint4*)(pA1 + 32);
    uint4 p2a = *(const uint4*)(pA0 + 64);  uint4 p2b = *(const uint4*)(pA1 + 64);
    asm volatile("s_waitcnt vmcnt(0)" ::: "memory");
    __builtin_amdgcn_s_barrier();

#define STEP(kt_, ktl_, pa_, pb_) do {                                          \
        bf16x8 bfv[4];                                                          \
        _Pragma("unroll")                                                       \
        for (int j_ = 0; j_ < 4; j_++) {                                        \
            const int cl_ = j_ * 16 + fr;                                       \
            const int unit_ = ((ktl_) * 4 + kg) ^ (cl_ & 7);                    \
            bfv[j_] = *(const bf16x8*)&Bs[(cl_ * 48 + unit_) * 8];              \
        }                                                                       \
        bf16x8 av0_ = __builtin_bit_cast(bf16x8, pa_);                          \
        bf16x8 av1_ = __builtin_bit_cast(bf16x8, pb_);                          \
        if ((kt_) + 3 < NKT) {                                                  \
            pa_ = *(const uint4*)(pA0 + ((kt_) + 3) * 32);                      \
            pb_ = *(const uint4*)(pA1 + ((kt_) + 3) * 32);                      \
        }                                                                       \
        _Pragma("unroll")                                                       \
        for (int j_ = 0; j_ < 4; j_++) {                                        \
            acc[0][j_] = __builtin_amdgcn_mfma_f32_16x16x32_bf16(av0_, bfv[j_], acc[0][j_], 0, 0, 0); \
            acc[1][j_] = __builtin_amdgcn_mfma_f32_16x16x32_bf16(av1_, bfv[j_], acc[1][j_], 0, 0, 0); \
        }                                                                       \
    } while (0)

#pragma unroll
    for (int h = 0; h < NH; h++) {
        if (h > 0) {
            __syncthreads();          // all waves done with previous B half
            stageB(h * 384);
            asm volatile("s_waitcnt vmcnt(0)" ::: "memory");
            __builtin_amdgcn_s_barrier();
        }
#pragma unroll
        for (int kq = 0; kq < 4; kq++) {
            STEP(h * 12 + kq * 3 + 0, kq * 3 + 0, p0a, p0b);
            STEP(h * 12 + kq * 3 + 1, kq * 3 + 1, p1a, p1b);
            STEP(h * 12 + kq * 3 + 2, kq * 3 + 2, p2a, p2b);
        }
    }
#undef STEP

    float bv[4];
#pragma unroll
    for (int j = 0; j < 4; j++) bv[j] = bias[cb + j * 16 + fr];
    const int kg4 = kg * 4;
    const int rbase = strip * 128;

    if (EPI == 1) {
        // stage C through dead B-LDS (stride 72 shorts: 16B-aligned rows)
        __syncthreads();
        unsigned short* Ct = Bs;
#pragma unroll
        for (int i = 0; i < 2; i++) {
            const int rl = wid * 32 + i * 16 + kg4;
#pragma unroll
            for (int j = 0; j < 4; j++) {
#pragma unroll
                for (int rr = 0; rr < 4; rr++)
                    Ct[(rl + rr) * 72 + j * 16 + fr] = f2bf(gelu_(acc[i][j][rr] + bv[j]));
            }
        }
        __syncthreads();
#pragma unroll
        for (int s_ = 0; s_ < 4; s_++) {
            int u = s_ * 256 + t;
            int rl = u >> 3, seg = u & 7;
            int grow = rbase + rl;
            if (grow < M)
                *(uint4*)(outb + (size_t)grow * ldo + cb + seg * 8) =
                    *(const uint4*)&Ct[rl * 72 + seg * 8];
        }
    } else {
#pragma unroll
        for (int i = 0; i < 2; i++) {
            const int rb = rbase + wid * 32 + i * 16 + kg4;
#pragma unroll
            for (int rr = 0; rr < 4; rr++) {
                const int row = rb + rr;
                if (row < M) {
#pragma unroll
                    for (int j = 0; j < 4; j++) {
                        size_t o = (size_t)row * ldo + cb + j * 16 + fr;
                        outf[o] = xres[o] + gelu_(acc[i][j][rr] + bv[j]);
                    }
                }
            }
        }
    }
}

// ---- R4 2-phase dbuf GEMM (270us measured) for the edge linear ----
// EPI 3: outb[pose[row]] = bf16(acc+bias)
template <int EPI, bool ABF16>
__global__ __launch_bounds__(256) void gemm_fused(
    const void* __restrict__ Ap, const unsigned short* __restrict__ Bt,
    const float* __restrict__ bias, int M, int K, int ncols,
    const int* __restrict__ pose,
    unsigned short* __restrict__ outb,
    const float* __restrict__ xres, float* __restrict__ outf, int ldo) {
    __shared__ __align__(16) unsigned short As[2][128 * 32];
    __shared__ __align__(16) unsigned short Bs[2][128 * 32];
    const int t = threadIdx.x;
    const int nwg = gridDim.x;
    const int orig = blockIdx.x;
    const int xcd = orig & 7;
    const int q = nwg >> 3, r = nwg & 7;
    const int wgid = (xcd < r ? xcd * (q + 1) : r * (q + 1) + (xcd - r) * q) + (orig >> 3);
    const int pp = wgid / ncols;
    const int m0 = pp * 128;
    const int n0 = (wgid - pp * ncols) * 128;

    const int lane = t & 63;
    const int wid = t >> 6;
    const int wr = (wid >> 1) << 6;
    const int wc = (wid & 1) << 6;
    const int fr = lane & 15;
    const int kg = lane >> 4;
    const int crow = lane >> 2;
    const int cseg = lane & 3;
    const int sr = t >> 1;
    const int sh = (t & 1) << 4;

    f32x4 acc[4][4];
#pragma unroll
    for (int i = 0; i < 4; i++)
#pragma unroll
        for (int j = 0; j < 4; j++) acc[i][j] = (f32x4){0.f, 0.f, 0.f, 0.f};

    const bool arok = (m0 + sr) < M;
    const size_t arowoff = (size_t)(m0 + sr) * K;
    const int NT = K >> 5;

    auto stageB = [&](int buf, int k0) {
#pragma unroll
        for (int h = 0; h < 2; h++) {
            const int rbase = wid * 32 + h * 16;
            gload16(Bt + (size_t)(n0 + rbase + crow) * K + k0 + cseg * 8,
                    &Bs[buf][rbase * 32]);
        }
    };
    auto stageA16 = [&](int buf, int k0) {
        const unsigned short* Ab = (const unsigned short*)Ap;
#pragma unroll
        for (int h = 0; h < 2; h++) {
            const int rbase = wid * 32 + h * 16;
            if (m0 + rbase + crow < M)
                gload16(Ab + (size_t)(m0 + rbase + crow) * K + k0 + cseg * 8,
                        &As[buf][rbase * 32]);
        }
    };

    if (ABF16) {
        stageA16(0, 0);
    } else if (arok) {
        const float4* p = (const float4*)((const float*)Ap + arowoff + sh);
        float4 f0 = p[0], f1 = p[1], f2 = p[2], f3 = p[3];
        uint4 w0, w1;
        w0.x = pk2(f0.x, f0.y); w0.y = pk2(f0.z, f0.w);
        w0.z = pk2(f1.x, f1.y); w0.w = pk2(f1.z, f1.w);
        w1.x = pk2(f2.x, f2.y); w1.y = pk2(f2.z, f2.w);
        w1.z = pk2(f3.x, f3.y); w1.w = pk2(f3.z, f3.w);
        *(uint4*)&As[0][sr * 32 + sh] = w0;
        *(uint4*)&As[0][sr * 32 + sh + 8] = w1;
    }
    stageB(0, 0);
    __syncthreads();

    int cur = 0;
    for (int kt = 0; kt < NT; ++kt) {
        const int nxt = cur ^ 1;
        const bool more = (kt + 1) < NT;
        float4 f0, f1, f2, f3;
        if (more) {
            const int k0n = (kt + 1) * 32;
            if (ABF16) {
                stageA16(nxt, k0n);
            } else if (arok) {
                const float4* p = (const float4*)((const float*)Ap + arowoff + k0n + sh);
                f0 = p[0]; f1 = p[1]; f2 = p[2]; f3 = p[3];
            }
            stageB(nxt, k0n);
        }

        bf16x8 a[4], b[4];
#pragma unroll
        for (int i = 0; i < 4; i++) a[i] = *(const bf16x8*)&As[cur][(wr + i * 16 + fr) * 32 + kg * 8];
#pragma unroll
        for (int j = 0; j < 4; j++) b[j] = *(const bf16x8*)&Bs[cur][(wc + j * 16 + fr) * 32 + kg * 8];
#pragma unroll
        for (int i = 0; i < 4; i++)
#pragma unroll
            for (int j = 0; j < 4; j++)
                acc[i][j] = __builtin_amdgcn_mfma_f32_16x16x32_bf16(a[i], b[j], acc[i][j], 0, 0, 0);

        if (!ABF16 && more && arok) {
            uint4 w0, w1;
            w0.x = pk2(f0.x, f0.y); w0.y = pk2(f0.z, f0.w);
            w0.z = pk2(f1.x, f1.y); w0.w = pk2(f1.z, f1.w);
            w1.x = pk2(f2.x, f2.y); w1.y = pk2(f2.z, f2.w);
            w1.z = pk2(f3.x, f3.y); w1.w = pk2(f3.z, f3.w);
            *(uint4*)&As[nxt][sr * 32 + sh] = w0;
            *(uint4*)&As[nxt][sr * 32 + sh + 8] = w1;
        }
        __syncthreads();
        cur = nxt;
    }

    const int kg4 = kg * 4;
#pragma unroll
    for (int i = 0; i < 4; i++) {
        const int rb = m0 + wr + i * 16 + kg4;
#pragma unroll
        for (int j = 0; j < 4; j++) {
            const int c = n0 + wc + j * 16 + fr;
#pragma unroll
            for (int r = 0; r < 4; r++) {
                const int row = rb + r;
                if (row < M) {
                    float v = acc[i][j][r] + bias[c];
                    if (EPI == 2) {
                        size_t o = (size_t)row * ldo + c;
                        outf[o] = xres[o] + gelu_(v);
                    } else {
                        outb[(size_t)pose[row] * ldo + c] = f2bf(v);
                    }
                }
            }
        }
    }
}

extern "C" void kernel_launch(void* const* d_in, const int* in_sizes, int n_in,
                              void* d_out, int out_size, void* d_ws, size_t ws_size,
                              hipStream_t stream) {
    const float* x = (const float*)d_in[0];
    const float* ea = (const float*)d_in[1];
    const float* gamma = (const float*)d_in[2];
    const float* beta = (const float*)d_in[3];
    const float* epsp = (const float*)d_in[4];
    const float* W_edge = (const float*)d_in[5];
    const float* b_edge = (const float*)d_in[6];
    const float* W1 = (const float*)d_in[7];
    const float* b1 = (const float*)d_in[8];
    const float* W2 = (const float*)d_in[9];
    const float* b2 = (const float*)d_in[10];
    const int* eidx = (const int*)d_in[11];
    float* out = (float*)d_out;
    const int N = in_sizes[0] / Df;
    const int E = in_sizes[1] / Df;
    const int* esrc = eidx;
    const int* edst = eidx + E;

    char* w = (char*)d_ws;
    size_t off_ = 0;
    auto alloc = [&](size_t bytes) { char* p = w + off_; off_ += (bytes + 255) & ~(size_t)255; return p; };
    float* stats = (float*)alloc(2 * Df * sizeof(float));
    float* coef = (float*)alloc(2 * Df * sizeof(float));
    unsigned short* hb = (unsigned short*)alloc((size_t)N * Df * 2);
    unsigned short* zb = (unsigned short*)alloc((size_t)N * Df * 2);
    unsigned short* tb = (unsigned short*)alloc((size_t)N * Hf * 2);
    unsigned short* WeT = (unsigned short*)alloc((size_t)Df * Df * 2);
    unsigned short* W1T = (unsigned short*)alloc((size_t)Df * Hf * 2);
    unsigned short* W2T = (unsigned short*)alloc((size_t)Hf * Df * 2);
    int* deg = (int*)alloc((size_t)(N + 1) * 4);      // reused as fill cursor
    int* offs = (int*)alloc((size_t)(N + 1) * 4);
    int* srcp = (int*)alloc((size_t)E * 4);
    int* pose = (int*)alloc((size_t)E * 4);
    int* sums = (int*)alloc(64 * 4);
    size_t msgl_bytes = (size_t)E * Df * 2;
    unsigned short* msgl;
    if (off_ + msgl_bytes <= ws_size) msgl = (unsigned short*)alloc(msgl_bytes);
    else msgl = (unsigned short*)d_out;   // dead until final GEMM writes it
    (void)n_in; (void)out_size;

    hipMemsetAsync(stats, 0, 2 * Df * sizeof(float), stream);
    hipMemsetAsync(deg, 0, (size_t)N * 4, stream);

    // BN + h
    bn_stats<<<1024, 192, 0, stream>>>(x, stats, N);
    bn_finalize<<<1, Df, 0, stream>>>(stats, gamma, beta, coef, N);
    int tot8 = N * Df / 8;
    h_kernel<<<(tot8 + 255) / 256, 256, 0, stream>>>(x, coef, hb, tot8);

    // weights (one dispatch)
    wtrans3<<<(Df * Df + 2 * Df * Hf + 255) / 256, 256, 0, stream>>>(
        W_edge, W1, W2, WeT, W1T, W2T);

    // CSR by dst
    int nb = (N + SCAN_CH - 1) / SCAN_CH;
    degree_k<<<(E + 255) / 256, 256, 0, stream>>>(edst, deg, E);
    scan1<<<nb, 256, 0, stream>>>(deg, offs, sums, N);
    scan2<<<1, 1, 0, stream>>>(sums, nb);
    scan3<<<(N + 256) / 256, 256, 0, stream>>>(offs, sums, N, nb);
    hipMemcpyAsync(deg, offs, (size_t)N * 4, hipMemcpyDeviceToDevice, stream);
    fill_k<<<(E + 255) / 256, 256, 0, stream>>>(edst, esrc, deg, srcp, pose, E);

    // edge linear: msgl[pose[e]] = ea[e] @ We^T + b_edge  (f32 A path, bf16 out)
    int ep = (E + 127) / 128;
    gemm_fused<3, false><<<dim3(ep * (Df / 128)), 256, 0, stream>>>(
        ea, WeT, b_edge, E, Df, Df / 128, pose, msgl, nullptr, nullptr, Df);

    // gather-reduce -> z (bf16)
    aggregate<<<2048, 256, 0, stream>>>(msgl, hb, offs, srcp, epsp, zb, N);

    // GEMM1 (strip, depth-3): tb = bf16(gelu(zb @ W1T^T + b1))
    int strips = (N + 127) / 128;
    gemm_strip<Df, 1><<<dim3(strips * (Hf / 64)), 256, 0, stream>>>(
        zb, W1T, b1, tb, nullptr, nullptr, N, Hf / 64, Hf);

    // GEMM2 (strip, K=768 two halves, depth-3): out = x + gelu(tb @ W2T^T + b2)
    gemm_strip<Hf, 2><<<dim3(strips * (Df / 64)), 256, 0, stream>>>(
        tb, W2T, b2, nullptr, x, out, N, Df / 64, Df);
}